// Round 3
// baseline (225.553 us; speedup 1.0000x reference)
//
#include <hip/hip_runtime.h>
#include <math.h>

#define B 8
#define D 256
#define N_LIVE 10000
#define K_NEW 32
#define KC 10032
#define KC4 2508            // KC/4
#define NS 100
#define NROW 101            // 100 bootstrap rows + 1 plain-softmax row (the score)
#define EPS 0.1f
#define CAPA 255            // active-set capacity (u8 lut encoding); true actives ~32/b
#define ACT_CUT 87.0f       // exp(-87)=1.65e-38: below fp32-normal -> weight 0 anyway
#define LBLK 314            // k_logits blocks per b (32 particles each; last partial)
#define BMAX_STRIDE 320

// ---- workspace layout in floats ----
#define WS_BMAX   0                            // B*320 floats: per-block maxima
#define WS_LOGITS (WS_BMAX + B * BMAX_STRIDE)  // B*KC floats
#define WS_BOOT   (WS_LOGITS + B * KC)         // B*NROW*D floats
#define WS_DONE   (WS_BOOT + B * NROW * D)     // B uints: rows-done counters

// NOTE (r8 lesson, prior session): hipLaunchCooperativeKernel does NOT work in
// this harness (graph-capture rejects it). Keep discrete stream-ordered
// dispatches. NOTE (r4 lesson): global atomicMax onto 8 lines serialized ~50us
// -> keep the two-level max. NOTE (this session r0->r2): removing k_select +
// prefetching boot_idx gave EXACTLY zero delta (170.44 -> 170.47 us) -> the
// timed window is dominated by ~48us 320MB workspace re-poison fills, not by
// our ~26us of kernel work. This round: merge k_final into k_boot (last-block
// epilogue) as the discriminating experiment; if delta ~0 again, we are at the
// controllable floor.

// ---------------- kernel 1: logits[b,k] + per-block max ----------------
// 8 particles per wave (32/block): 8 independent 1KB row loads in flight,
// 8 interleaved shuffle-reduce chains. Block (0,b) also zeroes done[b].
__global__ __launch_bounds__(256) void k_logits(
    const float* __restrict__ xt, const float* __restrict__ live_x0,
    const float* __restrict__ live_ll, const float* __restrict__ x0n,
    const float* __restrict__ lln, const float* __restrict__ ts_p,
    float* __restrict__ logits, float* __restrict__ bmax,
    unsigned* __restrict__ done) {
  int b = blockIdx.y;
  if (blockIdx.x == 0 && threadIdx.x == 0) done[b] = 0;
  int w = threadIdx.x >> 6;
  int lane = threadIdx.x & 63;
  int k0 = blockIdx.x * 32 + w * 8;
  bool valid = (k0 < KC);
  int kb = valid ? k0 : 0;                 // safe dup loads for the dead waves
  float4 c = ((const float4*)(xt + b * D))[lane];

  float s[8];
#pragma unroll
  for (int p = 0; p < 8; p++) {
    int k = kb + p;
    const float* src = (k < N_LIVE)
        ? (live_x0 + ((size_t)b * N_LIVE + k) * D)
        : (x0n + ((size_t)b * K_NEW + (k - N_LIVE)) * D);
    float4 v = ((const float4*)src)[lane];
    float dx = v.x - c.x, dy = v.y - c.y, dz = v.z - c.z, dw = v.w - c.w;
    s[p] = dx * dx + dy * dy + dz * dz + dw * dw;
  }
#pragma unroll
  for (int off = 32; off; off >>= 1) {     // 8 interleaved chains hide DS latency
#pragma unroll
    for (int p = 0; p < 8; p++) s[p] += __shfl_xor(s[p], off);
  }
  __shared__ float wlog[4];
  if (lane == 0) {
    float ts = *ts_p;
    float inv2 = 0.5f / (ts * ts), lts = logf(ts);
    float o[8];
#pragma unroll
    for (int p = 0; p < 8; p++) {
      int k = kb + p;
      o[p] = (k < N_LIVE)
          ? live_ll[(size_t)b * N_LIVE + k] - s[p] * inv2 - lts
          : lln[(size_t)b * K_NEW + (k - N_LIVE)];   // gaussian corr cancels exactly
    }
    if (valid) {
      float4 o0 = {o[0], o[1], o[2], o[3]}, o1 = {o[4], o[5], o[6], o[7]};
      *(float4*)(logits + (size_t)b * KC + kb) = o0;
      *(float4*)(logits + (size_t)b * KC + kb + 4) = o1;
      wlog[w] = fmaxf(fmaxf(fmaxf(o[0], o[1]), fmaxf(o[2], o[3])),
                      fmaxf(fmaxf(o[4], o[5]), fmaxf(o[6], o[7])));
    } else {
      wlog[w] = -INFINITY;
    }
  }
  __syncthreads();
  if (threadIdx.x == 0)
    bmax[b * BMAX_STRIDE + blockIdx.x] =
        fmaxf(fmaxf(wlog[0], wlog[1]), fmaxf(wlog[2], wlog[3]));
}

// -------- kernel 2: select + count + weighted sum + last-block epilogue ----
// One block per (n,b). Phases P0..P4 as before; then rocPRIM-style
// last-block-per-b handoff: store boot row -> __threadfence (release) ->
// tid0 atomicAdd(done[b]) -> the block seeing NROW-1 acquires (__threadfence)
// and runs the std/convergence epilogue for b, writing out directly.
__global__ __launch_bounds__(256) void k_boot(
    const float* __restrict__ live_x0, const float* __restrict__ x0n,
    const float* __restrict__ logits, const float* __restrict__ bmax,
    const int* __restrict__ boot_idx, float* __restrict__ boot,
    unsigned* __restrict__ done, const float* __restrict__ xt,
    const float* __restrict__ ts_p, float* __restrict__ out) {
  int n = blockIdx.x;   // 0..100
  int b = blockIdx.y;
  int tid = threadIdx.x;
  int nw = tid >> 6, lane = tid & 63;
  __shared__ unsigned slut32[KC4];        // u8 lut, packed 4/word (10032 B)
  __shared__ float se[CAPA + 1];          // exp(l - M) per active
  __shared__ int sidx[CAPA + 1];          // particle index per active
  __shared__ int cnt[CAPA + 1];           // bootstrap multiplicity
  __shared__ float4 part[4][64];
  __shared__ float sred[4];
  __shared__ int sacnt;
  __shared__ int slast;

  // ---- P0: per-b max + boot_idx prefetch (independent, overlapped) ----
  float m = -INFINITY;
  for (int i = tid; i < LBLK; i += 256) m = fmaxf(m, bmax[b * BMAX_STRIDE + i]);
#pragma unroll
  for (int off = 32; off; off >>= 1) m = fmaxf(m, __shfl_xor(m, off));
  if (lane == 0) sred[nw] = m;
  if (tid == 0) sacnt = 0;

  int4 pre[10];
  if (n < NS) {
    const int4* brow = (const int4*)(boot_idx + ((size_t)n * B + b) * KC);
#pragma unroll
    for (int i = 0; i < 10; i++) {
      int k4 = tid + i * 256;
      if (k4 < KC4) pre[i] = brow[k4];
    }
  }
  __syncthreads();
  float M = fmaxf(fmaxf(sred[0], sred[1]), fmaxf(sred[2], sred[3]));
  float thr = M - ACT_CUT;

  // ---- P1: scan logits, build lut + active set in LDS ----
  const float4* lg4 = (const float4*)(logits + (size_t)b * KC);
  cnt[tid] = (n < NS) ? 0 : 1;            // CAPA+1 == 256 entries
#pragma unroll
  for (int i = 0; i < 10; i++) {
    int k4 = tid + i * 256;
    if (k4 < KC4) {
      float4 l4 = lg4[k4];
      unsigned pack = 0;
      float le; int pos;
      le = l4.x; if (le > thr) { pos = atomicAdd(&sacnt, 1); if (pos < CAPA) {
          se[pos] = expf(le - M); sidx[pos] = 4 * k4;     pack |= (unsigned)(pos + 1); } }
      le = l4.y; if (le > thr) { pos = atomicAdd(&sacnt, 1); if (pos < CAPA) {
          se[pos] = expf(le - M); sidx[pos] = 4 * k4 + 1; pack |= (unsigned)(pos + 1) << 8; } }
      le = l4.z; if (le > thr) { pos = atomicAdd(&sacnt, 1); if (pos < CAPA) {
          se[pos] = expf(le - M); sidx[pos] = 4 * k4 + 2; pack |= (unsigned)(pos + 1) << 16; } }
      le = l4.w; if (le > thr) { pos = atomicAdd(&sacnt, 1); if (pos < CAPA) {
          se[pos] = expf(le - M); sidx[pos] = 4 * k4 + 3; pack |= (unsigned)(pos + 1) << 24; } }
      slut32[k4] = pack;
    }
  }
  __syncthreads();
  int A = min(sacnt, CAPA);

  // ---- P2: count draws hitting the active set ----
  const unsigned char* lutb = (const unsigned char*)slut32;
  if (n < NS) {
#pragma unroll
    for (int i = 0; i < 10; i++) {
      int k4 = tid + i * 256;
      if (k4 < KC4) {
        int4 v = pre[i];
        int t;
        t = lutb[v.x]; if (t) atomicAdd(&cnt[t - 1], 1);
        t = lutb[v.y]; if (t) atomicAdd(&cnt[t - 1], 1);
        t = lutb[v.z]; if (t) atomicAdd(&cnt[t - 1], 1);
        t = lutb[v.w]; if (t) atomicAdd(&cnt[t - 1], 1);
      }
    }
  }
  __syncthreads();

  // ---- P3: denominator ----
  float dnum = (tid < A) ? (float)cnt[tid] * se[tid] : 0.f;
#pragma unroll
  for (int off = 32; off; off >>= 1) dnum += __shfl_xor(dnum, off);
  if (lane == 0) sred[nw] = dnum;
  __syncthreads();
  float inv = 1.f / (sred[0] + sred[1] + sred[2] + sred[3]);

  // ---- P4: weighted sum over active rows (wave-uniform cnt skip) ----
  const float* lx = live_x0 + (size_t)b * N_LIVE * D;
  const float* nx = x0n + (size_t)b * K_NEW * D;
  float4 a0 = {0.f, 0.f, 0.f, 0.f};
  for (int p = nw; p < A; p += 4) {
    int c = cnt[p];
    if (!c) continue;                     // p is wave-uniform -> no divergence
    float w = (float)c * se[p];
    int j = sidx[p];
    const float4* r = (const float4*)((j < N_LIVE) ? (lx + (size_t)j * D)
                                                   : (nx + (size_t)(j - N_LIVE) * D));
    float4 v = r[lane];
    a0.x = fmaf(w, v.x, a0.x); a0.y = fmaf(w, v.y, a0.y);
    a0.z = fmaf(w, v.z, a0.z); a0.w = fmaf(w, v.w, a0.w);
  }
  part[nw][lane] = a0;
  __syncthreads();
  if (nw == 0) {
    float4 q0 = part[0][lane], q1 = part[1][lane], q2 = part[2][lane], q3 = part[3][lane];
    float4 r;
    r.x = ((q0.x + q1.x) + (q2.x + q3.x)) * inv;
    r.y = ((q0.y + q1.y) + (q2.y + q3.y)) * inv;
    r.z = ((q0.z + q1.z) + (q2.z + q3.z)) * inv;
    r.w = ((q0.w + q1.w) + (q2.w + q3.w)) * inv;
    ((float4*)(boot + ((size_t)b * NROW + n) * D))[lane] = r;
  }

  // ---- handoff: release row, count arrivals, last block runs epilogue ----
  __threadfence();                         // release: row store visible device-wide
  __syncthreads();                         // all lanes past the store+fence
  if (tid == 0) slast = (atomicAdd(&done[b], 1) == NROW - 1) ? 1 : 0;
  __syncthreads();
  if (!slast) return;
  __threadfence();                         // acquire: see all other blocks' rows

  // ---- epilogue (one block per b): two-pass std + convergence + score ----
  // tid == column d. Rows are L2/L3-hot (just written). Two-pass std
  // preserved (no sumsq cancellation risk).
  int d = tid;                             // 0..255
  float ts = *ts_p;
  const float* bb = boot + (size_t)b * NROW * D + d;
  float s0 = 0.f, s1 = 0.f, s2 = 0.f, s3 = 0.f;
#pragma unroll 4
  for (int i = 0; i < NS; i += 4) {        // NS==100, 4 | 100
    s0 += bb[(size_t)(i) * D];
    s1 += bb[(size_t)(i + 1) * D];
    s2 += bb[(size_t)(i + 2) * D];
    s3 += bb[(size_t)(i + 3) * D];
  }
  float mean = ((s0 + s1) + (s2 + s3)) / (float)NS;
  float v0 = 0.f, v1 = 0.f, v2 = 0.f, v3 = 0.f;
#pragma unroll 4
  for (int i = 0; i < NS; i += 4) {
    float t0 = bb[(size_t)(i) * D] - mean;
    float t1 = bb[(size_t)(i + 1) * D] - mean;
    float t2 = bb[(size_t)(i + 2) * D] - mean;
    float t3 = bb[(size_t)(i + 3) * D] - mean;
    v0 = fmaf(t0, t0, v0); v1 = fmaf(t1, t1, v1);
    v2 = fmaf(t2, t2, v2); v3 = fmaf(t3, t3, v3);
  }
  float var = ((v0 + v1) + (v2 + v3)) / (float)(NS - 1);
  float sigma_raw = sqrtf(var);
  // std((x - xt)/ts) = std(x)/ts (ts>0); condition: sigma_v < EPS*ts
  bool ok = (sigma_raw / ts) < (EPS * ts);
  // score = (sum_k w*x - xt)/ts  since sum_k w == 1
  out[(size_t)b * D + d] = (bb[(size_t)NS * D] - xt[(size_t)b * D + d]) / ts;
  unsigned long long mba = __ballot(ok);
  __shared__ int wok[4];
  if (lane == 0) wok[nw] = (mba == 0xFFFFFFFFFFFFFFFFull) ? 1 : 0;
  __syncthreads();
  if (tid == 0)
    out[(size_t)B * D + b] = (wok[0] & wok[1] & wok[2] & wok[3]) ? 1.0f : 0.0f;
}

extern "C" void kernel_launch(void* const* d_in, const int* in_sizes, int n_in,
                              void* d_out, int out_size, void* d_ws, size_t ws_size,
                              hipStream_t stream) {
  const float* xt       = (const float*)d_in[0];
  const float* live_x0  = (const float*)d_in[1];
  const float* live_ll  = (const float*)d_in[2];
  const float* x0n      = (const float*)d_in[3];
  const float* lln      = (const float*)d_in[4];
  const float* ts_p     = (const float*)d_in[5];
  const int*   boot_idx = (const int*)d_in[6];
  float* out = (float*)d_out;
  float* ws  = (float*)d_ws;

  float* bmax    = ws + WS_BMAX;
  float* logits  = ws + WS_LOGITS;
  float* boot    = ws + WS_BOOT;
  unsigned* done = (unsigned*)(ws + WS_DONE);

  k_logits<<<dim3(LBLK, B), 256, 0, stream>>>(xt, live_x0, live_ll, x0n, lln, ts_p, logits, bmax, done);
  k_boot<<<dim3(NROW, B), 256, 0, stream>>>(live_x0, x0n, logits, bmax, boot_idx, boot, done, xt, ts_p, out);
}

// Round 4
// 169.340 us; speedup vs baseline: 1.3320x; 1.3320x over previous
//
#include <hip/hip_runtime.h>
#include <math.h>

#define B 8
#define D 256
#define N_LIVE 10000
#define K_NEW 32
#define KC 10032
#define KC4 2508            // KC/4
#define NS 100
#define NROW 101            // 100 bootstrap rows + 1 plain-softmax row (the score)
#define EPS 0.1f
#define CAP 256             // active-set capacity slots (u8 lut encoding uses 1..255)
#define CAPA 255
#define ACT_CUT 87.0f       // exp(-87)=1.65e-38: below fp32-normal -> weight 0 anyway
#define LBLK 314            // k_logits blocks per b (32 particles each; last partial)
#define BMAX_STRIDE 320

// ---- workspace layout in floats ----
// hdr (uints): cnt[b]@[0..7], live_active_flag[b]@[8..15], M[b] bits@[16..23]
#define WS_HDR    0                            // 160 uints (slack for stability)
#define WS_BMAX   160                          // B*320 floats: per-block maxima
#define WS_LOGITS (WS_BMAX + B * BMAX_STRIDE)  // B*KC floats
#define WS_ACTE   (WS_LOGITS + B * KC)         // B*CAP floats: e_j = exp(l-M)
#define WS_ACTI   (WS_ACTE + B * CAP)          // B*CAP ints: particle index j
#define WS_LUT    (WS_ACTI + B * CAP)          // B*KC u8 bytes = B*KC/4 floats
#define WS_BOOT   (WS_LUT + B * KC / 4)        // B*NROW*D floats

// SESSION NOTES:
// r0->r2: removing k_select + reg-prefetch = EXACTLY 0 delta (170.44->170.47).
// r3: last-block epilogue w/ __threadfence = +55us total; k_boot 85us with
//     hbm 2.9%, VALU 2.9%, occ 24% -> k_boot is PURE LATENCY; device-scope
//     fence per block (L2 writeback, non-coherent XCD L2s) was the regression.
//     Additivity r3 confirms decomposition: fills~96 + k_logits~20 +
//     k_boot~45 + k_final~3 + gaps ~= 170. k_boot is the target.
// r4 (this): flag-gated fast path -- for this data the active set is exactly
//     the 32 new particles (live logits ~ -1000; reference fp32 softmax gives
//     them weight 0 by underflow), so counting = register compare, no LDS lut.
//     General lut path kept behind the flag for adversarial inputs.
// NOTE (prior session r8): hipLaunchCooperativeKernel rejected by harness
// graph capture. NOTE (prior r4): global atomicMax onto 8 lines ~50us.

// ---------------- kernel 1: logits[b,k] + per-block max ----------------
// 8 particles per wave (32/block): 8 independent 1KB row loads in flight,
// 8 interleaved shuffle-reduce chains. Block (0,b) zeroes hdr cnt+flag.
__global__ __launch_bounds__(256) void k_logits(
    const float* __restrict__ xt, const float* __restrict__ live_x0,
    const float* __restrict__ live_ll, const float* __restrict__ x0n,
    const float* __restrict__ lln, const float* __restrict__ ts_p,
    float* __restrict__ logits, float* __restrict__ bmax,
    unsigned* __restrict__ hdr) {
  int b = blockIdx.y;
  if (blockIdx.x == 0 && threadIdx.x == 0) { hdr[b] = 0; hdr[8 + b] = 0; }
  int w = threadIdx.x >> 6;
  int lane = threadIdx.x & 63;
  int k0 = blockIdx.x * 32 + w * 8;
  bool valid = (k0 < KC);
  int kb = valid ? k0 : 0;                 // safe dup loads for the dead waves
  float4 c = ((const float4*)(xt + b * D))[lane];

  float s[8];
#pragma unroll
  for (int p = 0; p < 8; p++) {
    int k = kb + p;
    const float* src = (k < N_LIVE)
        ? (live_x0 + ((size_t)b * N_LIVE + k) * D)
        : (x0n + ((size_t)b * K_NEW + (k - N_LIVE)) * D);
    float4 v = ((const float4*)src)[lane];
    float dx = v.x - c.x, dy = v.y - c.y, dz = v.z - c.z, dw = v.w - c.w;
    s[p] = dx * dx + dy * dy + dz * dz + dw * dw;
  }
#pragma unroll
  for (int off = 32; off; off >>= 1) {     // 8 interleaved chains hide DS latency
#pragma unroll
    for (int p = 0; p < 8; p++) s[p] += __shfl_xor(s[p], off);
  }
  __shared__ float wlog[4];
  if (lane == 0) {
    float ts = *ts_p;
    float inv2 = 0.5f / (ts * ts), lts = logf(ts);
    float o[8];
#pragma unroll
    for (int p = 0; p < 8; p++) {
      int k = kb + p;
      o[p] = (k < N_LIVE)
          ? live_ll[(size_t)b * N_LIVE + k] - s[p] * inv2 - lts
          : lln[(size_t)b * K_NEW + (k - N_LIVE)];   // gaussian corr cancels exactly
    }
    if (valid) {
      float4 o0 = {o[0], o[1], o[2], o[3]}, o1 = {o[4], o[5], o[6], o[7]};
      *(float4*)(logits + (size_t)b * KC + kb) = o0;
      *(float4*)(logits + (size_t)b * KC + kb + 4) = o1;
      wlog[w] = fmaxf(fmaxf(fmaxf(o[0], o[1]), fmaxf(o[2], o[3])),
                      fmaxf(fmaxf(o[4], o[5]), fmaxf(o[6], o[7])));
    } else {
      wlog[w] = -INFINITY;
    }
  }
  __syncthreads();
  if (threadIdx.x == 0)
    bmax[b * BMAX_STRIDE + blockIdx.x] =
        fmaxf(fmaxf(wlog[0], wlog[1]), fmaxf(wlog[2], wlog[3]));
}

// ------- kernel 2: max-reduce + active-set select + live-active flag -------
// 8 blocks per b; each redundantly reduces the 314 per-block maxima then
// selects. Writes M to hdr (block 0), sets hdr flag if any LIVE particle is
// active (-> k_boot must take the general lut path). ~32 actives expected.
__global__ __launch_bounds__(256) void k_select(
    const float* __restrict__ logits, const float* __restrict__ bmax,
    unsigned* __restrict__ hdr, float* __restrict__ act_e,
    int* __restrict__ act_idx, unsigned char* __restrict__ lut) {
  int b = blockIdx.y;
  __shared__ float sm[4];
  float m = -INFINITY;
  for (int i = threadIdx.x; i < LBLK; i += 256)
    m = fmaxf(m, bmax[b * BMAX_STRIDE + i]);
#pragma unroll
  for (int off = 32; off; off >>= 1) m = fmaxf(m, __shfl_xor(m, off));
  if ((threadIdx.x & 63) == 0) sm[threadIdx.x >> 6] = m;
  __syncthreads();
  float M = fmaxf(fmaxf(sm[0], sm[1]), fmaxf(sm[2], sm[3]));
  if (blockIdx.x == 0 && threadIdx.x == 0) hdr[16 + b] = __float_as_uint(M);
  float thr = M - ACT_CUT;

  int tid = blockIdx.x * 256 + threadIdx.x;
  const float* lg = logits + (size_t)b * KC;
  unsigned* cnt = &hdr[b];
  for (int k = tid; k < KC; k += 8 * 256) {
    float l = lg[k];
    unsigned char v = 0;
    if (l > thr) {
      if (k < N_LIVE) atomicOr(&hdr[8 + b], 1u);   // forces general path
      int pos = (int)atomicAdd(cnt, 1u);           // rare: ~32 per b total
      if (pos < CAPA) {
        act_e[b * CAP + pos] = expf(l - M);
        act_idx[b * CAP + pos] = k;
        v = (unsigned char)(pos + 1);
      }
    }
    lut[(size_t)b * KC + k] = v;
  }
}

// -------- kernel 3: count + sparse weighted sum (flag-gated fast path) ------
// One block per (n,b), 512 threads (8 waves). boot row prefetched into 5 int4
// regs up front (HBM latency hides under setup).
// FAST path (flag==0, the actual data): actives are exactly the K_NEW new
//   particles; slot = idx - N_LIVE; counting is a register compare + rare LDS
//   atomic. No bmax reduce, no logits scan, no lut build, no LDS staging.
// GENERAL path (flag!=0): stage the u8 global lut (10KB, coalesced u32) and
//   active arrays into LDS, count via ds byte lookups (round-2-validated).
// n==100 is the identity row (plain softmax -> final score).
__global__ __launch_bounds__(512) void k_boot(
    const float* __restrict__ live_x0, const float* __restrict__ x0n,
    const float* __restrict__ logits, const unsigned* __restrict__ hdr,
    const float* __restrict__ act_e, const int* __restrict__ act_idx,
    const unsigned char* __restrict__ lut, const int* __restrict__ boot_idx,
    float* __restrict__ boot) {
  int n = blockIdx.x;   // 0..100
  int b = blockIdx.y;
  int tid = threadIdx.x;
  int nw = tid >> 6, lane = tid & 63;
  __shared__ unsigned slut32[KC4];        // general path only (10032 B)
  __shared__ float se[CAP];
  __shared__ int sidx[CAP];
  __shared__ int cnt[CAP];
  __shared__ float4 part[8][64];
  __shared__ float sred[8];

  int flag = (int)hdr[8 + b];
  float M = __uint_as_float(hdr[16 + b]);
  int A;

  int4 pre[5];
  if (n < NS) {
    const int4* brow = (const int4*)(boot_idx + ((size_t)n * B + b) * KC);
#pragma unroll
    for (int i = 0; i < 5; i++) {
      int k4 = tid + i * 512;
      if (k4 < KC4) pre[i] = brow[k4];
    }
  }

  if (flag == 0) {
    // ---- fast path ----
    A = K_NEW;
    if (tid < K_NEW) {
      se[tid] = expf(logits[(size_t)b * KC + N_LIVE + tid] - M);
      sidx[tid] = N_LIVE + tid;
      cnt[tid] = (n < NS) ? 0 : 1;
    }
    __syncthreads();
    if (n < NS) {
#pragma unroll
      for (int i = 0; i < 5; i++) {
        int k4 = tid + i * 512;
        if (k4 < KC4) {
          int4 v = pre[i];
          if (v.x >= N_LIVE) atomicAdd(&cnt[v.x - N_LIVE], 1);
          if (v.y >= N_LIVE) atomicAdd(&cnt[v.y - N_LIVE], 1);
          if (v.z >= N_LIVE) atomicAdd(&cnt[v.z - N_LIVE], 1);
          if (v.w >= N_LIVE) atomicAdd(&cnt[v.w - N_LIVE], 1);
        }
      }
    }
  } else {
    // ---- general path ----
    A = min((int)hdr[b], CAPA);
    for (int i = tid; i < A; i += 512) {
      se[i] = act_e[b * CAP + i];
      sidx[i] = act_idx[b * CAP + i];
      cnt[i] = (n < NS) ? 0 : 1;
    }
    const unsigned* gl = (const unsigned*)(lut + (size_t)b * KC);
    for (int i = tid; i < KC4; i += 512) slut32[i] = gl[i];
    __syncthreads();
    const unsigned char* lutb = (const unsigned char*)slut32;
    if (n < NS) {
#pragma unroll
      for (int i = 0; i < 5; i++) {
        int k4 = tid + i * 512;
        if (k4 < KC4) {
          int4 v = pre[i];
          int t;
          t = lutb[v.x]; if (t) atomicAdd(&cnt[t - 1], 1);
          t = lutb[v.y]; if (t) atomicAdd(&cnt[t - 1], 1);
          t = lutb[v.z]; if (t) atomicAdd(&cnt[t - 1], 1);
          t = lutb[v.w]; if (t) atomicAdd(&cnt[t - 1], 1);
        }
      }
    }
  }
  __syncthreads();

  // ---- denominator ----
  float d = (tid < A) ? (float)cnt[tid] * se[tid] : 0.f;
#pragma unroll
  for (int off = 32; off; off >>= 1) d += __shfl_xor(d, off);
  if (lane == 0) sred[nw] = d;
  __syncthreads();
  float inv = 1.f / (((sred[0] + sred[1]) + (sred[2] + sred[3])) +
                     ((sred[4] + sred[5]) + (sred[6] + sred[7])));

  // ---- weighted sum over active rows (wave-uniform cnt skip) ----
  const float* lx = live_x0 + (size_t)b * N_LIVE * D;
  const float* nx = x0n + (size_t)b * K_NEW * D;
  float4 a0 = {0.f, 0.f, 0.f, 0.f};
  for (int p = nw; p < A; p += 8) {
    int c = cnt[p];
    if (!c) continue;                     // p is wave-uniform -> no divergence
    float w = (float)c * se[p];
    int j = sidx[p];
    const float4* r = (const float4*)((j < N_LIVE) ? (lx + (size_t)j * D)
                                                   : (nx + (size_t)(j - N_LIVE) * D));
    float4 v = r[lane];
    a0.x = fmaf(w, v.x, a0.x); a0.y = fmaf(w, v.y, a0.y);
    a0.z = fmaf(w, v.z, a0.z); a0.w = fmaf(w, v.w, a0.w);
  }
  part[nw][lane] = a0;
  __syncthreads();
  if (nw == 0) {
    float4 q0 = part[0][lane], q1 = part[1][lane];
    float4 q2 = part[2][lane], q3 = part[3][lane];
    float4 q4 = part[4][lane], q5 = part[5][lane];
    float4 q6 = part[6][lane], q7 = part[7][lane];
    float4 r;
    r.x = (((q0.x + q1.x) + (q2.x + q3.x)) + ((q4.x + q5.x) + (q6.x + q7.x))) * inv;
    r.y = (((q0.y + q1.y) + (q2.y + q3.y)) + ((q4.y + q5.y) + (q6.y + q7.y))) * inv;
    r.z = (((q0.z + q1.z) + (q2.z + q3.z)) + ((q4.z + q5.z) + (q6.z + q7.z))) * inv;
    r.w = (((q0.w + q1.w) + (q2.w + q3.w)) + ((q4.w + q5.w) + (q6.w + q7.w))) * inv;
    ((float4*)(boot + ((size_t)b * NROW + n) * D))[lane] = r;
  }
}

// ---------------- kernel 4: std over bootstrap rows + epilogue ----------------
// 1024 threads: 4 row-stripes of 25. Two-pass std preserved (no sumsq
// cancellation risk).
__global__ __launch_bounds__(1024) void k_final(
    const float* __restrict__ boot, const float* __restrict__ xt,
    const float* __restrict__ ts_p, float* __restrict__ out) {
  int b = blockIdx.x;
  int tid = threadIdx.x;
  int d = tid & 255;
  int st = tid >> 8;                 // stripe 0..3: rows st, st+4, ...
  float ts = *ts_p;
  const float* bb = boot + (size_t)b * NROW * D + d;
  __shared__ float red[4][256];
  __shared__ float mrow[256];
  __shared__ int wok[4];
  float s = 0.f;
#pragma unroll 5
  for (int i = 0; i < 25; i++) s += bb[(size_t)(st + 4 * i) * D];
  red[st][d] = s;
  __syncthreads();
  if (st == 0) mrow[d] = (red[0][d] + red[1][d] + red[2][d] + red[3][d]) / (float)NS;
  __syncthreads();
  float mean = mrow[d];
  float vs = 0.f;
#pragma unroll 5
  for (int i = 0; i < 25; i++) {
    float t = bb[(size_t)(st + 4 * i) * D] - mean;
    vs += t * t;
  }
  red[st][d] = vs;
  __syncthreads();
  if (st == 0) {                     // waves 0..3 entirely inside (tid<256)
    float var = (red[0][d] + red[1][d] + red[2][d] + red[3][d]) / (float)(NS - 1);
    float sigma_raw = sqrtf(var);
    // std((x - xt)/ts) = std(x)/ts (ts>0); condition: sigma_v < EPS*ts
    bool ok = (sigma_raw / ts) < (EPS * ts);
    // score = (sum_k w*x - xt)/ts  since sum_k w == 1
    out[(size_t)b * D + d] = (bb[(size_t)NS * D] - xt[(size_t)b * D + d]) / ts;
    unsigned long long mba = __ballot(ok);
    if ((d & 63) == 0) wok[d >> 6] = (mba == 0xFFFFFFFFFFFFFFFFull) ? 1 : 0;
  }
  __syncthreads();
  if (tid == 0)
    out[(size_t)B * D + b] = (wok[0] & wok[1] & wok[2] & wok[3]) ? 1.0f : 0.0f;
}

extern "C" void kernel_launch(void* const* d_in, const int* in_sizes, int n_in,
                              void* d_out, int out_size, void* d_ws, size_t ws_size,
                              hipStream_t stream) {
  const float* xt       = (const float*)d_in[0];
  const float* live_x0  = (const float*)d_in[1];
  const float* live_ll  = (const float*)d_in[2];
  const float* x0n      = (const float*)d_in[3];
  const float* lln      = (const float*)d_in[4];
  const float* ts_p     = (const float*)d_in[5];
  const int*   boot_idx = (const int*)d_in[6];
  float* out = (float*)d_out;
  float* ws  = (float*)d_ws;

  unsigned* hdr       = (unsigned*)(ws + WS_HDR);
  float* bmax         = ws + WS_BMAX;
  float* logits       = ws + WS_LOGITS;
  float* act_e        = ws + WS_ACTE;
  int*   act_idx      = (int*)(ws + WS_ACTI);
  unsigned char* lut  = (unsigned char*)(ws + WS_LUT);
  float* boot         = ws + WS_BOOT;

  k_logits<<<dim3(LBLK, B), 256, 0, stream>>>(xt, live_x0, live_ll, x0n, lln, ts_p, logits, bmax, hdr);
  k_select<<<dim3(8, B), 256, 0, stream>>>(logits, bmax, hdr, act_e, act_idx, lut);
  k_boot<<<dim3(NROW, B), 512, 0, stream>>>(live_x0, x0n, logits, hdr, act_e, act_idx, lut, boot_idx, boot);
  k_final<<<dim3(B), 1024, 0, stream>>>(boot, xt, ts_p, out);
}